// Round 5
// baseline (179.803 us; speedup 1.0000x reference)
//
#include <hip/hip_runtime.h>
#include <math.h>

#define B_ 2
#define L_ 2048
#define H_ 16
#define E_ 64
#define D_ 64
#define DM_ 512
#define DH_ 256

typedef __bf16 bf16_t;
typedef bf16_t bf16x8_t __attribute__((ext_vector_type(8)));
typedef float f32x4_t __attribute__((ext_vector_type(4)));

// pack two floats to bf16x2 (round-up-at-halfway; 2 add + 1 perm)
__device__ __forceinline__ unsigned bpack(float hi, float lo) {
    unsigned uh = __float_as_uint(hi) + 0x8000u;
    unsigned ul = __float_as_uint(lo) + 0x8000u;
    return __builtin_amdgcn_perm(uh, ul, 0x07060302u);
}

__device__ __forceinline__ bf16_t to_bf16(float f) {
    union { float f; unsigned u; } x; x.f = f;
    unsigned r = (x.u + 0x7fffu + ((x.u >> 16) & 1u)) >> 16;
    union { unsigned short s; bf16_t b; } y; y.s = (unsigned short)r;
    return y.b;
}

// async 16B global->LDS copy; HW dest = (wave-uniform base) + lane*16
__device__ __forceinline__ void gload_lds16(const bf16_t* g, bf16_t* l) {
    __builtin_amdgcn_global_load_lds(
        (const __attribute__((address_space(1))) unsigned int*)g,
        (__attribute__((address_space(3))) unsigned int*)l, 16, 0, 0);
}

// K row permutation (makes swapped-QK^T S-values land in PV A-frag layout):
// p(s) = s[1:0] | s[3]<<2 | s[4]<<3 | s[2]<<4 | s[5]<<5
__device__ __forceinline__ int permK(int sl) {
    return (sl & 3) | (((sl >> 3) & 1) << 2) | (((sl >> 4) & 1) << 3)
         | (((sl >> 2) & 1) << 4) | (((sl >> 5) & 1) << 5);
}

// ---------------- prep: w1 transpose + K/V bf16 conversion + fused zero -----
__global__ __launch_bounds__(256) void prep_kernel(
        const float* __restrict__ w1, bf16_t* __restrict__ w1t,
        const float* __restrict__ K, bf16_t* __restrict__ Kp,
        const float* __restrict__ V, bf16_t* __restrict__ Vs,
        float* __restrict__ fused) {
    __shared__ bf16_t T[64][88];       // V transpose tile (stride avoids conflicts)
    const int bidx = blockIdx.x;
    const int t = threadIdx.x;

    if (bidx < 256) {                  // ---- w1t ----
        const int n = bidx;
        #pragma unroll
        for (int u = 0; u < 2; ++u) {
            int k = t + u * 256;
            w1t[(size_t)n * DM_ + k] = to_bf16(w1[(size_t)k * DH_ + n]);
        }
        if (bidx == 0) {               // zero-init fused for mlp atomics
            #pragma unroll
            for (int u = 0; u < 16; ++u) fused[t + u * 256] = 0.f;
        }
        return;
    }

    if (bidx < 1280) {                 // ---- K convert ----
        const int idx = bidx - 256;
        const int bh = idx >> 5, tile = idx & 31;
        const int b = bh >> 4, h = bh & 15;
        const int sl = t >> 2, e0 = (t & 3) << 4;
        const float* src = K + (((size_t)b * L_ + tile * 64 + sl) * H_ + h) * E_ + e0;
        f32x4_t v0 = *(const f32x4_t*)(src);
        f32x4_t v1 = *(const f32x4_t*)(src + 4);
        f32x4_t v2 = *(const f32x4_t*)(src + 8);
        f32x4_t v3 = *(const f32x4_t*)(src + 12);
        uint4 lo, hi;
        lo.x = bpack(v0[1], v0[0]); lo.y = bpack(v0[3], v0[2]);
        lo.z = bpack(v1[1], v1[0]); lo.w = bpack(v1[3], v1[2]);
        hi.x = bpack(v2[1], v2[0]); hi.y = bpack(v2[3], v2[2]);
        hi.z = bpack(v3[1], v3[0]); hi.w = bpack(v3[3], v3[2]);
        const int r = permK(sl);
        const int bb = r & 7;          // low row bits -> bank spread
        bf16_t* drow = Kp + ((size_t)(bh * 32 + tile) * 64 + r) * 64;
        *(uint4*)(drow + ((((e0 >> 3)    ) ^ bb) << 3)) = lo;
        *(uint4*)(drow + ((((e0 >> 3) + 1) ^ bb) << 3)) = hi;
        return;
    }

    {                                  // ---- V convert/transpose ----
        const int idx = bidx - 1280;
        const int bh = idx >> 5, tile = idx & 31;
        const int b = bh >> 4, h = bh & 15;
        const int sl = t >> 2, d0 = (t & 3) << 4;
        const float* src = V + (((size_t)b * L_ + tile * 64 + sl) * H_ + h) * D_ + d0;
        f32x4_t v0 = *(const f32x4_t*)(src);
        f32x4_t v1 = *(const f32x4_t*)(src + 4);
        f32x4_t v2 = *(const f32x4_t*)(src + 8);
        f32x4_t v3 = *(const f32x4_t*)(src + 12);
        uint4 lo, hi;
        lo.x = bpack(v0[1], v0[0]); lo.y = bpack(v0[3], v0[2]);
        lo.z = bpack(v1[1], v1[0]); lo.w = bpack(v1[3], v1[2]);
        hi.x = bpack(v2[1], v2[0]); hi.y = bpack(v2[3], v2[2]);
        hi.z = bpack(v3[1], v3[0]); hi.w = bpack(v3[3], v3[2]);
        *(uint4*)&T[sl][d0]     = lo;
        *(uint4*)&T[sl][d0 + 8] = hi;
        __syncthreads();
        const int d = t & 63, bd = d & 7;  // low row bits -> bank spread
        bf16_t* drow = Vs + ((size_t)bh * 64 + d) * 2048 + tile * 64;
        #pragma unroll
        for (int gg = 0; gg < 2; ++gg) {
            int qb = (t >> 6) + gg * 4;
            int slb = (qb ^ bd) << 3;        // content(slot q) = V[(q^bd)*8+j][d]
            union { unsigned short u[8]; uint4 q; } acc;
            #pragma unroll
            for (int j = 0; j < 8; ++j) {
                union { bf16_t b; unsigned short s; } x; x.b = T[slb + j][d];
                acc.u[j] = x.s;
            }
            *(uint4*)(drow + qb * 8) = acc.q;
        }
    }
}

// ---------------- MLP via MFMA, 4-way n-split: 1024 blocks -------------------
// block = 16 rows x 64-n quarter; wave owns 16 n. Partials combined by
// atomicAdd (b2 dropped: it cancels in the momentum diff; fused zeroed in prep)
__global__ __launch_bounds__(256) void mlp_kernel(
        const float* __restrict__ raw, const bf16_t* __restrict__ w1t,
        const float* __restrict__ b1, const float* __restrict__ w2,
        float* __restrict__ fused) {
    __shared__ bf16_t Rs[16][520];
    __shared__ float part[4][16];
    const int t = threadIdx.x;
    const int m0 = (blockIdx.x >> 2) * 16;
    const int nq = blockIdx.x & 3;     // n-quarter
    #pragma unroll
    for (int u = 0; u < 8; ++u) {
        int idx = t + u * 256;
        int row = idx >> 7;
        int k = (idx & 127) << 2;
        f32x4_t v = *(const f32x4_t*)&raw[(size_t)(m0 + row) * DM_ + k];
        uint2 p;
        p.x = bpack(v[1], v[0]);
        p.y = bpack(v[3], v[2]);
        *(uint2*)&Rs[row][k] = p;
    }
    __syncthreads();
    const int wave = t >> 6;
    const int lane = t & 63;
    const int lrow = lane & 15;
    const int lgrp = lane >> 4;
    const int n = nq * 64 + wave * 16 + lrow;

    f32x4_t acc = (f32x4_t){0.f, 0.f, 0.f, 0.f};
    const bf16_t* wbase = w1t + (size_t)n * DM_ + lgrp * 8;
    #pragma unroll
    for (int s = 0; s < 16; ++s) {
        bf16x8_t a = *(const bf16x8_t*)&Rs[lrow][s * 32 + lgrp * 8];
        bf16x8_t b = *(const bf16x8_t*)(wbase + s * 32);
        acc = __builtin_amdgcn_mfma_f32_16x16x32_bf16(a, b, acc, 0, 0, 0);
    }
    // epilogue: relu + w2 partial, reduce over this block's 64 n
    const float b1v = b1[n];
    const float w2v = w2[n];
    float rowpart[4];
    #pragma unroll
    for (int r = 0; r < 4; ++r) {
        float h = acc[r] + b1v;
        h = h > 0.f ? h : 0.f;
        rowpart[r] = h * w2v;
    }
    #pragma unroll
    for (int r = 0; r < 4; ++r) {
        float v = rowpart[r];
        v += __shfl_xor(v, 1);
        v += __shfl_xor(v, 2);
        v += __shfl_xor(v, 4);
        v += __shfl_xor(v, 8);
        if (lrow == 0) part[wave][lgrp * 4 + r] = v;
    }
    __syncthreads();
    if (t < 16)
        atomicAdd(&fused[m0 + t], part[0][t] + part[1][t] + part[2][t] + part[3][t]);
}

// ---------------- flash attention, QBLK=128: 2 q-frags per wave --------------
// 512 blocks x 4 waves; wave owns 32 q-rows (2 MFMA row-frags). K/V ds_reads
// and staging shared by both frags -> wave-steps halved vs QBLK=64.
__global__ __launch_bounds__(256) void attn_kernel(
        const float* __restrict__ Q, const bf16_t* __restrict__ Kp,
        const bf16_t* __restrict__ Vs, const float* __restrict__ fused,
        const float* __restrict__ alpha_trend, float* __restrict__ out) {
    __shared__ __align__(16) bf16_t Ks[2][64][64];
    __shared__ __align__(16) bf16_t Vt[2][64][64];
    __shared__ float moms[2][64];

    const int bid = blockIdx.x;
    const int bh  = bid & 31;
    const int grp = bid >> 5;          // 0..15 q-pair tile
    // stride-256 balanced pairing: blocks b and b+256 share a CU slot and get
    // t summing to 15 -> constant 34 steps per CU slot.
    const int tq  = (grp < 8) ? grp : 23 - grp;
    const int h = bh & 15, b = bh >> 4;
    const int q0 = tq << 7;
    const int nsteps = 2 * tq + 2;
    const int tid = threadIdx.x;
    const int wave = tid >> 6, lane = tid & 63;
    const int lrow = lane & 15, lgrp = lane >> 4;

    const float c1 = 0.18033688f;      // 0.125 * log2(e)
    const float ascale2 = alpha_trend[h] * c1;
    const size_t bl = (size_t)b * L_;
    const int qw0 = q0 + wave * 32;    // wave's 32 q-rows

    const bf16_t* Kb = Kp + (size_t)bh * 131072;   // 32 tiles * 4096 el
    const bf16_t* Vb = Vs + (size_t)bh * 131072;   // 64 rows * 2048 el
    const float* fusedp = fused + bl;

    // Q fragments for rows qw0+lrow (frag0) and qw0+16+lrow (frag1)
    bf16x8_t a_lo, a_hi, c_lo, c_hi;
    {
        const float* qp = Q + ((bl + qw0 + lrow) * H_ + h) * E_ + lgrp * 8;
        f32x4_t v0 = *(const f32x4_t*)(qp);
        f32x4_t v1 = *(const f32x4_t*)(qp + 4);
        f32x4_t v2 = *(const f32x4_t*)(qp + 32);
        f32x4_t v3 = *(const f32x4_t*)(qp + 36);
        const float* qp2 = qp + 16 * H_ * E_;
        f32x4_t w0 = *(const f32x4_t*)(qp2);
        f32x4_t w1v = *(const f32x4_t*)(qp2 + 4);
        f32x4_t w2v = *(const f32x4_t*)(qp2 + 32);
        f32x4_t w3 = *(const f32x4_t*)(qp2 + 36);
        #pragma unroll
        for (int k = 0; k < 4; ++k) {
            a_lo[k]     = to_bf16(v0[k] * c1);
            a_lo[4 + k] = to_bf16(v1[k] * c1);
            a_hi[k]     = to_bf16(v2[k] * c1);
            a_hi[4 + k] = to_bf16(v3[k] * c1);
            c_lo[k]     = to_bf16(w0[k] * c1);
            c_lo[4 + k] = to_bf16(w1v[k] * c1);
            c_hi[k]     = to_bf16(w2v[k] * c1);
            c_hi[4 + k] = to_bf16(w3[k] * c1);
        }
    }
    const int qg  = qw0 + lrow;
    const int qg2 = qg + 16;
    const float mq  = (qg == 0) ? 0.f : fusedp[qg] - fusedp[qg - 1];
    const float mq2 = fusedp[qg2] - fusedp[qg2 - 1];

    // per-lane staging sources (global layout == LDS layout, linear copy)
    const bf16_t* ksrc = Kb + wave * 512 + lane * 8;
    const bf16_t* vsrc = Vb + (size_t)(wave * 8 + (lane >> 3)) * 2048 + (lane & 7) * 8;

    f32x4_t Oacc[4], Oacc2[4];
    #pragma unroll
    for (int c = 0; c < 4; ++c) {
        Oacc[c]  = (f32x4_t){0.f, 0.f, 0.f, 0.f};
        Oacc2[c] = (f32x4_t){0.f, 0.f, 0.f, 0.f};
    }
    float rowsum = 0.f, rowsum2 = 0.f;

    auto stage = [&](int t) {
        const int nb = t & 1;
        const bf16_t* kp0 = ksrc + (size_t)t * 4096;
        gload_lds16(kp0,        &Ks[nb][wave * 8][0]);
        gload_lds16(kp0 + 2048, &Ks[nb][wave * 8 + 32][0]);
        const bf16_t* vp0 = vsrc + t * 64;
        gload_lds16(vp0,               &Vt[nb][wave * 8][0]);
        gload_lds16(vp0 + 32 * 2048,   &Vt[nb][wave * 8 + 32][0]);
        if (tid < 64) {                 // momentum tile (wave 0)
            int s = t * 64 + tid;
            float f = fusedp[s];
            float fm = __shfl_up(f, 1);
            if (tid == 0) fm = (s == 0) ? f : fusedp[s - 1];
            moms[nb][tid] = f - fm;
        }
    };

    stage(0);
    for (int st = 0; st < nsteps; ++st) {
        const int buf = st & 1;
        __syncthreads();               // drains buf's async loads (vmcnt 0)
        if (st + 1 < nsteps) stage(st + 1);

        const int s0 = st << 6;
        if (s0 > qw0) continue;        // wave-uniform: whole tile masked

        const char* ksb = (const char*)&Ks[buf][0][0];
        const char* vtb = (const char*)&Vt[buf][0][0];
        const int bb = lrow & 7;       // read-side swizzle (matches prep)

        // S^T = K Q^T for both q-frags; K fragments shared
        f32x4_t Sacc[4], Sacc2[4];
        #pragma unroll
        for (int c = 0; c < 4; ++c) {
            Sacc[c]  = (f32x4_t){0.f, 0.f, 0.f, 0.f};
            Sacc2[c] = (f32x4_t){0.f, 0.f, 0.f, 0.f};
        }
        __builtin_amdgcn_s_setprio(1);
        #pragma unroll
        for (int c = 0; c < 4; ++c) {
            const char* kr = ksb + (c * 16 + lrow) * 128;
            bf16x8_t k_lo = *(const bf16x8_t*)(kr + ((lgrp ^ bb) << 4));
            bf16x8_t k_hi = *(const bf16x8_t*)(kr + (((4 + lgrp) ^ bb) << 4));
            Sacc[c]  = __builtin_amdgcn_mfma_f32_16x16x32_bf16(k_lo, a_lo, Sacc[c], 0, 0, 0);
            Sacc2[c] = __builtin_amdgcn_mfma_f32_16x16x32_bf16(k_lo, c_lo, Sacc2[c], 0, 0, 0);
            Sacc[c]  = __builtin_amdgcn_mfma_f32_16x16x32_bf16(k_hi, a_hi, Sacc[c], 0, 0, 0);
            Sacc2[c] = __builtin_amdgcn_mfma_f32_16x16x32_bf16(k_hi, c_hi, Sacc2[c], 0, 0, 0);
        }
        __builtin_amdgcn_s_setprio(0);

        // P = exp2(S - ascale2*|dm|) for both frags
        float rowe[4][4], rowe2[4][4];
        #pragma unroll
        for (int c = 0; c < 4; ++c) {
            const int sb = lgrp * 8 + ((c & 1) << 2) + ((c >> 1) << 5);
            f32x4_t ms4 = *(const f32x4_t*)&moms[buf][sb];
            #pragma unroll
            for (int r = 0; r < 4; ++r) {
                float arg  = Sacc[c][r]  - ascale2 * fabsf(mq  - ms4[r]);
                float arg2 = Sacc2[c][r] - ascale2 * fabsf(mq2 - ms4[r]);
                rowe[c][r]  = __builtin_amdgcn_exp2f(arg);
                rowe2[c][r] = __builtin_amdgcn_exp2f(arg2);
            }
        }
        if (qw0 - s0 < 64) {           // diagonal tiles: causal mask
            #pragma unroll
            for (int c = 0; c < 4; ++c) {
                const int sg0 = s0 + lgrp * 8 + ((c & 1) << 2) + ((c >> 1) << 5);
                #pragma unroll
                for (int r = 0; r < 4; ++r) {
                    if (sg0 + r > qg)  rowe[c][r]  = 0.f;
                    if (sg0 + r > qg2) rowe2[c][r] = 0.f;
                }
            }
        }
        #pragma unroll
        for (int c = 0; c < 4; ++c) {
            rowsum  += (rowe[c][0]  + rowe[c][1])  + (rowe[c][2]  + rowe[c][3]);
            rowsum2 += (rowe2[c][0] + rowe2[c][1]) + (rowe2[c][2] + rowe2[c][3]);
        }

        // O += P V for both frags; V fragments shared
        #pragma unroll
        for (int hh = 0; hh < 2; ++hh) {
            union { unsigned u[4]; bf16x8_t v; } pa, pa2;
            pa.u[0]  = bpack(rowe[2 * hh][1],      rowe[2 * hh][0]);
            pa.u[1]  = bpack(rowe[2 * hh][3],      rowe[2 * hh][2]);
            pa.u[2]  = bpack(rowe[2 * hh + 1][1],  rowe[2 * hh + 1][0]);
            pa.u[3]  = bpack(rowe[2 * hh + 1][3],  rowe[2 * hh + 1][2]);
            pa2.u[0] = bpack(rowe2[2 * hh][1],     rowe2[2 * hh][0]);
            pa2.u[1] = bpack(rowe2[2 * hh][3],     rowe2[2 * hh][2]);
            pa2.u[2] = bpack(rowe2[2 * hh + 1][1], rowe2[2 * hh + 1][0]);
            pa2.u[3] = bpack(rowe2[2 * hh + 1][3], rowe2[2 * hh + 1][2]);
            __builtin_amdgcn_s_setprio(1);
            #pragma unroll
            for (int c2 = 0; c2 < 4; ++c2) {
                const int row = c2 * 16 + lrow;
                bf16x8_t bv = *(const bf16x8_t*)(vtb + row * 128 +
                                                 (((hh * 4 + lgrp) ^ bb) << 4));
                Oacc[c2]  = __builtin_amdgcn_mfma_f32_16x16x32_bf16(pa.v,  bv, Oacc[c2],  0, 0, 0);
                Oacc2[c2] = __builtin_amdgcn_mfma_f32_16x16x32_bf16(pa2.v, bv, Oacc2[c2], 0, 0, 0);
            }
            __builtin_amdgcn_s_setprio(0);
        }
    }

    // epilogue: row sums (2 shuffles), normalize, store — both frags
    float rs = rowsum, rs2 = rowsum2;
    rs  += __shfl_xor(rs, 16);  rs  += __shfl_xor(rs, 32);
    rs2 += __shfl_xor(rs2, 16); rs2 += __shfl_xor(rs2, 32);
    #pragma unroll
    for (int r = 0; r < 4; ++r) {
        float inv  = 1.f / __shfl(rs,  lgrp * 4 + r);
        float inv2 = 1.f / __shfl(rs2, lgrp * 4 + r);
        size_t orow  = ((bl + qw0 + lgrp * 4 + r) * H_ + h) * D_;
        size_t orow2 = orow + (size_t)16 * H_ * D_;
        #pragma unroll
        for (int c = 0; c < 4; ++c) {
            out[orow  + c * 16 + lrow] = Oacc[c][r]  * inv;
            out[orow2 + c * 16 + lrow] = Oacc2[c][r] * inv2;
        }
    }
}

extern "C" void kernel_launch(void* const* d_in, const int* in_sizes, int n_in,
                              void* d_out, int out_size, void* d_ws, size_t ws_size,
                              hipStream_t stream) {
    const float* Q     = (const float*)d_in[0];
    const float* K     = (const float*)d_in[1];
    const float* V     = (const float*)d_in[2];
    const float* raw   = (const float*)d_in[3];
    const float* w1    = (const float*)d_in[4];
    const float* b1    = (const float*)d_in[5];
    const float* w2    = (const float*)d_in[6];
    const float* alpha = (const float*)d_in[8];
    float* out = (float*)d_out;

    float* fused = (float*)d_ws;                       // 4096 f32
    bf16_t* w1t  = (bf16_t*)(fused + B_ * L_);         // 256*512 bf16
    bf16_t* Kp   = w1t + 256 * 512;                    // 8 MB
    bf16_t* Vs   = Kp + (size_t)B_ * H_ * L_ * E_;     // 8 MB

    prep_kernel<<<2304, 256, 0, stream>>>(w1, w1t, K, Kp, V, Vs, fused);
    mlp_kernel<<<B_ * L_ / 16 * 4, 256, 0, stream>>>(raw, w1t, b1, w2, fused);
    attn_kernel<<<B_ * H_ * (L_ / 128), 256, 0, stream>>>(Q, Kp, Vs, fused, alpha, out);
}

// Round 6
// 169.561 us; speedup vs baseline: 1.0604x; 1.0604x over previous
//
#include <hip/hip_runtime.h>
#include <math.h>

#define B_ 2
#define L_ 2048
#define H_ 16
#define E_ 64
#define D_ 64
#define DM_ 512
#define DH_ 256

typedef __bf16 bf16_t;
typedef bf16_t bf16x8_t __attribute__((ext_vector_type(8)));
typedef float f32x4_t __attribute__((ext_vector_type(4)));

// pack two floats to bf16x2 (round-up-at-halfway; 2 add + 1 perm)
__device__ __forceinline__ unsigned bpack(float hi, float lo) {
    unsigned uh = __float_as_uint(hi) + 0x8000u;
    unsigned ul = __float_as_uint(lo) + 0x8000u;
    return __builtin_amdgcn_perm(uh, ul, 0x07060302u);
}

__device__ __forceinline__ bf16_t to_bf16(float f) {
    union { float f; unsigned u; } x; x.f = f;
    unsigned r = (x.u + 0x7fffu + ((x.u >> 16) & 1u)) >> 16;
    union { unsigned short s; bf16_t b; } y; y.s = (unsigned short)r;
    return y.b;
}

// async 16B global->LDS copy; HW dest = (wave-uniform base) + lane*16
__device__ __forceinline__ void gload_lds16(const bf16_t* g, bf16_t* l) {
    __builtin_amdgcn_global_load_lds(
        (const __attribute__((address_space(1))) unsigned int*)g,
        (__attribute__((address_space(3))) unsigned int*)l, 16, 0, 0);
}

// K row permutation (makes swapped-QK^T S-values land in PV A-frag layout):
// p(s) = s[1:0] | s[3]<<2 | s[4]<<3 | s[2]<<4 | s[5]<<5
__device__ __forceinline__ int permK(int sl) {
    return (sl & 3) | (((sl >> 3) & 1) << 2) | (((sl >> 4) & 1) << 3)
         | (((sl >> 2) & 1) << 4) | (((sl >> 5) & 1) << 5);
}

// ---------------- prep: w1 transpose + K/V bf16 conversion + fused zero -----
__global__ __launch_bounds__(256) void prep_kernel(
        const float* __restrict__ w1, bf16_t* __restrict__ w1t,
        const float* __restrict__ K, bf16_t* __restrict__ Kp,
        const float* __restrict__ V, bf16_t* __restrict__ Vs,
        float* __restrict__ fused) {
    __shared__ bf16_t T[64][88];       // V transpose tile (stride avoids conflicts)
    const int bidx = blockIdx.x;
    const int t = threadIdx.x;

    if (bidx < 256) {                  // ---- w1t ----
        const int n = bidx;
        #pragma unroll
        for (int u = 0; u < 2; ++u) {
            int k = t + u * 256;
            w1t[(size_t)n * DM_ + k] = to_bf16(w1[(size_t)k * DH_ + n]);
        }
        if (bidx == 0) {               // zero-init fused for mlp atomics
            #pragma unroll
            for (int u = 0; u < 16; ++u) fused[t + u * 256] = 0.f;
        }
        return;
    }

    if (bidx < 1280) {                 // ---- K convert ----
        const int idx = bidx - 256;
        const int bh = idx >> 5, tile = idx & 31;
        const int b = bh >> 4, h = bh & 15;
        const int sl = t >> 2, e0 = (t & 3) << 4;
        const float* src = K + (((size_t)b * L_ + tile * 64 + sl) * H_ + h) * E_ + e0;
        f32x4_t v0 = *(const f32x4_t*)(src);
        f32x4_t v1 = *(const f32x4_t*)(src + 4);
        f32x4_t v2 = *(const f32x4_t*)(src + 8);
        f32x4_t v3 = *(const f32x4_t*)(src + 12);
        uint4 lo, hi;
        lo.x = bpack(v0[1], v0[0]); lo.y = bpack(v0[3], v0[2]);
        lo.z = bpack(v1[1], v1[0]); lo.w = bpack(v1[3], v1[2]);
        hi.x = bpack(v2[1], v2[0]); hi.y = bpack(v2[3], v2[2]);
        hi.z = bpack(v3[1], v3[0]); hi.w = bpack(v3[3], v3[2]);
        const int r = permK(sl);
        const int bb = r & 7;          // low row bits -> bank spread
        bf16_t* drow = Kp + ((size_t)(bh * 32 + tile) * 64 + r) * 64;
        *(uint4*)(drow + ((((e0 >> 3)    ) ^ bb) << 3)) = lo;
        *(uint4*)(drow + ((((e0 >> 3) + 1) ^ bb) << 3)) = hi;
        return;
    }

    {                                  // ---- V convert/transpose ----
        const int idx = bidx - 1280;
        const int bh = idx >> 5, tile = idx & 31;
        const int b = bh >> 4, h = bh & 15;
        const int sl = t >> 2, d0 = (t & 3) << 4;
        const float* src = V + (((size_t)b * L_ + tile * 64 + sl) * H_ + h) * D_ + d0;
        f32x4_t v0 = *(const f32x4_t*)(src);
        f32x4_t v1 = *(const f32x4_t*)(src + 4);
        f32x4_t v2 = *(const f32x4_t*)(src + 8);
        f32x4_t v3 = *(const f32x4_t*)(src + 12);
        uint4 lo, hi;
        lo.x = bpack(v0[1], v0[0]); lo.y = bpack(v0[3], v0[2]);
        lo.z = bpack(v1[1], v1[0]); lo.w = bpack(v1[3], v1[2]);
        hi.x = bpack(v2[1], v2[0]); hi.y = bpack(v2[3], v2[2]);
        hi.z = bpack(v3[1], v3[0]); hi.w = bpack(v3[3], v3[2]);
        *(uint4*)&T[sl][d0]     = lo;
        *(uint4*)&T[sl][d0 + 8] = hi;
        __syncthreads();
        const int d = t & 63, bd = d & 7;  // low row bits -> bank spread
        bf16_t* drow = Vs + ((size_t)bh * 64 + d) * 2048 + tile * 64;
        #pragma unroll
        for (int gg = 0; gg < 2; ++gg) {
            int qb = (t >> 6) + gg * 4;
            int slb = (qb ^ bd) << 3;        // content(slot q) = V[(q^bd)*8+j][d]
            union { unsigned short u[8]; uint4 q; } acc;
            #pragma unroll
            for (int j = 0; j < 8; ++j) {
                union { bf16_t b; unsigned short s; } x; x.b = T[slb + j][d];
                acc.u[j] = x.s;
            }
            *(uint4*)(drow + qb * 8) = acc.q;
        }
    }
}

// ---------------- MLP via MFMA, 4-way n-split: 1024 blocks -------------------
__global__ __launch_bounds__(256) void mlp_kernel(
        const float* __restrict__ raw, const bf16_t* __restrict__ w1t,
        const float* __restrict__ b1, const float* __restrict__ w2,
        float* __restrict__ fused) {
    __shared__ bf16_t Rs[16][520];
    __shared__ float part[4][16];
    const int t = threadIdx.x;
    const int m0 = (blockIdx.x >> 2) * 16;
    const int nq = blockIdx.x & 3;     // n-quarter
    #pragma unroll
    for (int u = 0; u < 8; ++u) {
        int idx = t + u * 256;
        int row = idx >> 7;
        int k = (idx & 127) << 2;
        f32x4_t v = *(const f32x4_t*)&raw[(size_t)(m0 + row) * DM_ + k];
        uint2 p;
        p.x = bpack(v[1], v[0]);
        p.y = bpack(v[3], v[2]);
        *(uint2*)&Rs[row][k] = p;
    }
    __syncthreads();
    const int wave = t >> 6;
    const int lane = t & 63;
    const int lrow = lane & 15;
    const int lgrp = lane >> 4;
    const int n = nq * 64 + wave * 16 + lrow;

    f32x4_t acc = (f32x4_t){0.f, 0.f, 0.f, 0.f};
    const bf16_t* wbase = w1t + (size_t)n * DM_ + lgrp * 8;
    #pragma unroll
    for (int s = 0; s < 16; ++s) {
        bf16x8_t a = *(const bf16x8_t*)&Rs[lrow][s * 32 + lgrp * 8];
        bf16x8_t b = *(const bf16x8_t*)(wbase + s * 32);
        acc = __builtin_amdgcn_mfma_f32_16x16x32_bf16(a, b, acc, 0, 0, 0);
    }
    const float b1v = b1[n];
    const float w2v = w2[n];
    float rowpart[4];
    #pragma unroll
    for (int r = 0; r < 4; ++r) {
        float h = acc[r] + b1v;
        h = h > 0.f ? h : 0.f;
        rowpart[r] = h * w2v;
    }
    #pragma unroll
    for (int r = 0; r < 4; ++r) {
        float v = rowpart[r];
        v += __shfl_xor(v, 1);
        v += __shfl_xor(v, 2);
        v += __shfl_xor(v, 4);
        v += __shfl_xor(v, 8);
        if (lrow == 0) part[wave][lgrp * 4 + r] = v;
    }
    __syncthreads();
    if (t < 16)
        atomicAdd(&fused[m0 + t], part[0][t] + part[1][t] + part[2][t] + part[3][t]);
}

// ---------------- flash attention: QBLK=64, 2 s-tiles per barrier ------------
// R4 geometry (1024 blocks x 4 waves, best measured) but each barrier interval
// stages and computes TWO 64-key tiles: half the barriers, 2x independent
// work in flight between barriers. Momentum precomputed once into LDS.
__global__ __launch_bounds__(256) void attn_kernel(
        const float* __restrict__ Q, const bf16_t* __restrict__ Kp,
        const bf16_t* __restrict__ Vs, const float* __restrict__ fused,
        const float* __restrict__ alpha_trend, float* __restrict__ out) {
    __shared__ __align__(16) bf16_t Ks[2][128][64];   // [buf][2 tiles][perm rows]
    __shared__ __align__(16) bf16_t Vt[2][128][64];
    __shared__ __align__(16) float moms_all[2048];

    const int bid = blockIdx.x;
    const int bh  = bid & 31;
    const int grp = bid >> 5;
    // balanced pairing: consecutive bids alternate heavy/light (sum 32 steps)
    const int qt  = (grp & 1) ? (grp >> 1) : 31 - (grp >> 1);
    const int h = bh & 15, b = bh >> 4;
    const int q0 = qt << 6;
    const int npairs = (qt + 2) >> 1;  // 128-key pair-steps
    const int tid = threadIdx.x;
    const int wave = tid >> 6, lane = tid & 63;
    const int lrow = lane & 15, lgrp = lane >> 4;

    const float c1 = 0.18033688f;      // 0.125 * log2(e)
    const float ascale2 = alpha_trend[h] * c1;
    const size_t bl = (size_t)b * L_;
    const int qw0 = q0 + wave * 16;

    const bf16_t* Kb = Kp + (size_t)bh * 131072;   // 32 tiles * 4096 el
    const bf16_t* Vb = Vs + (size_t)bh * 131072;   // 64 rows * 2048 el
    const float* fusedp = fused + bl;

    // momentum table: built once, removes per-step global load + shuffle
    #pragma unroll
    for (int u = 0; u < 8; ++u) {
        int i = tid + u * 256;
        float f = fusedp[i];
        float fm = (i == 0) ? f : fusedp[i - 1];
        moms_all[i] = f - fm;
    }

    // Q fragments, prescaled by c1 (RNE, once)
    bf16x8_t a_lo, a_hi;
    {
        const float* qp = Q + ((bl + qw0 + lrow) * H_ + h) * E_ + lgrp * 8;
        f32x4_t v0 = *(const f32x4_t*)(qp);
        f32x4_t v1 = *(const f32x4_t*)(qp + 4);
        f32x4_t v2 = *(const f32x4_t*)(qp + 32);
        f32x4_t v3 = *(const f32x4_t*)(qp + 36);
        #pragma unroll
        for (int k = 0; k < 4; ++k) {
            a_lo[k]     = to_bf16(v0[k] * c1);
            a_lo[4 + k] = to_bf16(v1[k] * c1);
            a_hi[k]     = to_bf16(v2[k] * c1);
            a_hi[4 + k] = to_bf16(v3[k] * c1);
        }
    }
    const int qg = qw0 + lrow;
    const float mq = (qg == 0) ? 0.f : fusedp[qg] - fusedp[qg - 1];

    // per-lane staging sources (global layout == LDS layout, linear copy)
    const bf16_t* ksrc = Kb + wave * 512 + lane * 8;
    const bf16_t* vsrc = Vb + (size_t)(wave * 8 + (lane >> 3)) * 2048 + (lane & 7) * 8;

    f32x4_t Oacc[4];
    #pragma unroll
    for (int c = 0; c < 4; ++c) Oacc[c] = (f32x4_t){0.f, 0.f, 0.f, 0.f};
    float rowsum = 0.f;

    auto stage = [&](int p) {          // stage s-tiles 2p and 2p+1 into buf p&1
        const int nb = p & 1;
        const bf16_t* kp0 = ksrc + (size_t)p * 8192;
        gload_lds16(kp0,        &Ks[nb][wave * 8][0]);
        gload_lds16(kp0 + 2048, &Ks[nb][wave * 8 + 32][0]);
        gload_lds16(kp0 + 4096, &Ks[nb][64 + wave * 8][0]);
        gload_lds16(kp0 + 6144, &Ks[nb][64 + wave * 8 + 32][0]);
        const bf16_t* vp0 = vsrc + p * 128;
        gload_lds16(vp0,                  &Vt[nb][wave * 8][0]);
        gload_lds16(vp0 + 32 * 2048,      &Vt[nb][wave * 8 + 32][0]);
        gload_lds16(vp0 + 64,             &Vt[nb][64 + wave * 8][0]);
        gload_lds16(vp0 + 64 + 32 * 2048, &Vt[nb][64 + wave * 8 + 32][0]);
    };

    stage(0);
    for (int p = 0; p < npairs; ++p) {
        __syncthreads();               // drains buf's async loads (vmcnt 0)
        if (p + 1 < npairs) stage(p + 1);
        const int nb = p & 1;
        const int bb = lrow & 7;       // read-side swizzle (matches prep)

        #pragma unroll
        for (int sub = 0; sub < 2; ++sub) {
            const int tile = 2 * p + sub;
            const int s0 = tile << 6;
            if (s0 > qw0) continue;    // padding tile (wave-uniform skip)

            const char* ksb = (const char*)&Ks[nb][sub * 64][0];
            const char* vtb = (const char*)&Vt[nb][sub * 64][0];

            // S^T = K Q^T (swapped operands; log2 domain via Q prescale)
            f32x4_t Sacc[4];
            #pragma unroll
            for (int c = 0; c < 4; ++c) Sacc[c] = (f32x4_t){0.f, 0.f, 0.f, 0.f};
            __builtin_amdgcn_s_setprio(1);
            #pragma unroll
            for (int c = 0; c < 4; ++c) {
                const char* kr = ksb + (c * 16 + lrow) * 128;
                bf16x8_t k_lo = *(const bf16x8_t*)(kr + ((lgrp ^ bb) << 4));
                bf16x8_t k_hi = *(const bf16x8_t*)(kr + (((4 + lgrp) ^ bb) << 4));
                Sacc[c] = __builtin_amdgcn_mfma_f32_16x16x32_bf16(k_lo, a_lo, Sacc[c], 0, 0, 0);
                Sacc[c] = __builtin_amdgcn_mfma_f32_16x16x32_bf16(k_hi, a_hi, Sacc[c], 0, 0, 0);
            }
            __builtin_amdgcn_s_setprio(0);

            // P = exp2(S - ascale2*|dm|)
            float rowe[4][4];
            #pragma unroll
            for (int c = 0; c < 4; ++c) {
                const int sb = lgrp * 8 + ((c & 1) << 2) + ((c >> 1) << 5);
                f32x4_t ms4 = *(const f32x4_t*)&moms_all[s0 + sb];
                #pragma unroll
                for (int r = 0; r < 4; ++r) {
                    float arg = Sacc[c][r] - ascale2 * fabsf(mq - ms4[r]);
                    rowe[c][r] = __builtin_amdgcn_exp2f(arg);
                }
            }
            if (tile == qt) {          // causal mask on diagonal tile
                #pragma unroll
                for (int c = 0; c < 4; ++c) {
                    const int sg0 = s0 + lgrp * 8 + ((c & 1) << 2) + ((c >> 1) << 5);
                    #pragma unroll
                    for (int r = 0; r < 4; ++r)
                        if (sg0 + r > qg) rowe[c][r] = 0.f;
                }
            }
            #pragma unroll
            for (int c = 0; c < 4; ++c)
                rowsum += (rowe[c][0] + rowe[c][1]) + (rowe[c][2] + rowe[c][3]);

            // O += P V : P fragments lane-local, pack to bf16
            #pragma unroll
            for (int hh = 0; hh < 2; ++hh) {
                union { unsigned u[4]; bf16x8_t v; } pa;
                pa.u[0] = bpack(rowe[2 * hh][1],     rowe[2 * hh][0]);
                pa.u[1] = bpack(rowe[2 * hh][3],     rowe[2 * hh][2]);
                pa.u[2] = bpack(rowe[2 * hh + 1][1], rowe[2 * hh + 1][0]);
                pa.u[3] = bpack(rowe[2 * hh + 1][3], rowe[2 * hh + 1][2]);
                __builtin_amdgcn_s_setprio(1);
                #pragma unroll
                for (int c2 = 0; c2 < 4; ++c2) {
                    const int row = c2 * 16 + lrow;
                    bf16x8_t bv = *(const bf16x8_t*)(vtb + row * 128 +
                                                     (((hh * 4 + lgrp) ^ bb) << 4));
                    Oacc[c2] = __builtin_amdgcn_mfma_f32_16x16x32_bf16(pa.v, bv, Oacc[c2], 0, 0, 0);
                }
                __builtin_amdgcn_s_setprio(0);
            }
        }
    }

    // epilogue: full row sums via 2 shuffles, normalize, store
    float rs = rowsum;
    rs += __shfl_xor(rs, 16);
    rs += __shfl_xor(rs, 32);
    #pragma unroll
    for (int r = 0; r < 4; ++r) {
        float inv = 1.f / __shfl(rs, lgrp * 4 + r);
        size_t orow = ((bl + qw0 + lgrp * 4 + r) * H_ + h) * D_;
        #pragma unroll
        for (int c = 0; c < 4; ++c)
            out[orow + c * 16 + lrow] = Oacc[c][r] * inv;
    }
}

extern "C" void kernel_launch(void* const* d_in, const int* in_sizes, int n_in,
                              void* d_out, int out_size, void* d_ws, size_t ws_size,
                              hipStream_t stream) {
    const float* Q     = (const float*)d_in[0];
    const float* K     = (const float*)d_in[1];
    const float* V     = (const float*)d_in[2];
    const float* raw   = (const float*)d_in[3];
    const float* w1    = (const float*)d_in[4];
    const float* b1    = (const float*)d_in[5];
    const float* w2    = (const float*)d_in[6];
    const float* alpha = (const float*)d_in[8];
    float* out = (float*)d_out;

    float* fused = (float*)d_ws;                       // 4096 f32
    bf16_t* w1t  = (bf16_t*)(fused + B_ * L_);         // 256*512 bf16
    bf16_t* Kp   = w1t + 256 * 512;                    // 8 MB
    bf16_t* Vs   = Kp + (size_t)B_ * H_ * L_ * E_;     // 8 MB

    prep_kernel<<<2304, 256, 0, stream>>>(w1, w1t, K, Kp, V, Vs, fused);
    mlp_kernel<<<B_ * L_ / 16 * 4, 256, 0, stream>>>(raw, w1t, b1, w2, fused);
    attn_kernel<<<B_ * H_ * (L_ / 64), 256, 0, stream>>>(Q, Kp, Vs, fused, alpha, out);
}

// Round 7
// 166.959 us; speedup vs baseline: 1.0769x; 1.0156x over previous
//
#include <hip/hip_runtime.h>
#include <math.h>

#define B_ 2
#define L_ 2048
#define H_ 16
#define E_ 64
#define D_ 64
#define DM_ 512
#define DH_ 256

typedef __bf16 bf16_t;
typedef bf16_t bf16x8_t __attribute__((ext_vector_type(8)));
typedef float f32x4_t __attribute__((ext_vector_type(4)));

// pack two floats to bf16x2 (round-up-at-halfway; 2 add + 1 perm)
__device__ __forceinline__ unsigned bpack(float hi, float lo) {
    unsigned uh = __float_as_uint(hi) + 0x8000u;
    unsigned ul = __float_as_uint(lo) + 0x8000u;
    return __builtin_amdgcn_perm(uh, ul, 0x07060302u);
}

__device__ __forceinline__ bf16_t to_bf16(float f) {
    union { float f; unsigned u; } x; x.f = f;
    unsigned r = (x.u + 0x7fffu + ((x.u >> 16) & 1u)) >> 16;
    union { unsigned short s; bf16_t b; } y; y.s = (unsigned short)r;
    return y.b;
}

// async 16B global->LDS copy; HW dest = (wave-uniform base) + lane*16
__device__ __forceinline__ void gload_lds16(const bf16_t* g, bf16_t* l) {
    __builtin_amdgcn_global_load_lds(
        (const __attribute__((address_space(1))) unsigned int*)g,
        (__attribute__((address_space(3))) unsigned int*)l, 16, 0, 0);
}

// K row permutation (makes swapped-QK^T S-values land in PV A-frag layout):
// p(s) = s[1:0] | s[3]<<2 | s[4]<<3 | s[2]<<4 | s[5]<<5
__device__ __forceinline__ int permK(int sl) {
    return (sl & 3) | (((sl >> 3) & 1) << 2) | (((sl >> 4) & 1) << 3)
         | (((sl >> 2) & 1) << 4) | (((sl >> 5) & 1) << 5);
}

// ---------------- merged prep + MLP (no cross-block dependencies) ------------
// blocks [0,1024):    K [b][s][h][e] f32 -> Kp (perm + row&7 slot swizzle) bf16
// blocks [1024,2048): V -> Vs [bh][d][tile*64 + swizzled s] bf16
// blocks [2048,3072): mlp quarter: fused4[nq][m] = sum_n relu(raw@w1+b1)*w2
//                     (w1 read DIRECTLY, f32 -> unique-writer partials, no atomics)
__global__ __launch_bounds__(256) void prep_mlp_kernel(
        const float* __restrict__ K, bf16_t* __restrict__ Kp,
        const float* __restrict__ V, bf16_t* __restrict__ Vs,
        const float* __restrict__ raw, const float* __restrict__ w1,
        const float* __restrict__ b1, const float* __restrict__ w2,
        float* __restrict__ fused4) {
    __shared__ union {
        bf16_t T[64][88];              // V transpose tile
        struct { bf16_t Rs[16][520]; float part[4][16]; } m;
    } S;
    const int bidx = blockIdx.x;
    const int t = threadIdx.x;

    if (bidx < 1024) {                 // ---- K convert ----
        const int bh = bidx >> 5, tile = bidx & 31;
        const int b = bh >> 4, h = bh & 15;
        const int sl = t >> 2, e0 = (t & 3) << 4;
        const float* src = K + (((size_t)b * L_ + tile * 64 + sl) * H_ + h) * E_ + e0;
        f32x4_t v0 = *(const f32x4_t*)(src);
        f32x4_t v1 = *(const f32x4_t*)(src + 4);
        f32x4_t v2 = *(const f32x4_t*)(src + 8);
        f32x4_t v3 = *(const f32x4_t*)(src + 12);
        uint4 lo, hi;
        lo.x = bpack(v0[1], v0[0]); lo.y = bpack(v0[3], v0[2]);
        lo.z = bpack(v1[1], v1[0]); lo.w = bpack(v1[3], v1[2]);
        hi.x = bpack(v2[1], v2[0]); hi.y = bpack(v2[3], v2[2]);
        hi.z = bpack(v3[1], v3[0]); hi.w = bpack(v3[3], v3[2]);
        const int r = permK(sl);
        const int bb = r & 7;          // low row bits -> bank spread
        bf16_t* drow = Kp + ((size_t)(bh * 32 + tile) * 64 + r) * 64;
        *(uint4*)(drow + ((((e0 >> 3)    ) ^ bb) << 3)) = lo;
        *(uint4*)(drow + ((((e0 >> 3) + 1) ^ bb) << 3)) = hi;
        return;
    }

    if (bidx < 2048) {                 // ---- V convert/transpose ----
        const int idx = bidx - 1024;
        const int bh = idx >> 5, tile = idx & 31;
        const int b = bh >> 4, h = bh & 15;
        const int sl = t >> 2, d0 = (t & 3) << 4;
        const float* src = V + (((size_t)b * L_ + tile * 64 + sl) * H_ + h) * D_ + d0;
        f32x4_t v0 = *(const f32x4_t*)(src);
        f32x4_t v1 = *(const f32x4_t*)(src + 4);
        f32x4_t v2 = *(const f32x4_t*)(src + 8);
        f32x4_t v3 = *(const f32x4_t*)(src + 12);
        uint4 lo, hi;
        lo.x = bpack(v0[1], v0[0]); lo.y = bpack(v0[3], v0[2]);
        lo.z = bpack(v1[1], v1[0]); lo.w = bpack(v1[3], v1[2]);
        hi.x = bpack(v2[1], v2[0]); hi.y = bpack(v2[3], v2[2]);
        hi.z = bpack(v3[1], v3[0]); hi.w = bpack(v3[3], v3[2]);
        *(uint4*)&S.T[sl][d0]     = lo;
        *(uint4*)&S.T[sl][d0 + 8] = hi;
        __syncthreads();
        const int d = t & 63, bd = d & 7;  // low row bits -> bank spread
        bf16_t* drow = Vs + ((size_t)bh * 64 + d) * 2048 + tile * 64;
        #pragma unroll
        for (int gg = 0; gg < 2; ++gg) {
            int qb = (t >> 6) + gg * 4;
            int slb = (qb ^ bd) << 3;        // content(slot q) = V[(q^bd)*8+j][d]
            union { unsigned short u[8]; uint4 q; } acc;
            #pragma unroll
            for (int j = 0; j < 8; ++j) {
                union { bf16_t b; unsigned short s; } x; x.b = S.T[slb + j][d];
                acc.u[j] = x.s;
            }
            *(uint4*)(drow + qb * 8) = acc.q;
        }
        return;
    }

    {                                  // ---- mlp quarter (direct w1 reads) ----
        const int mb = bidx - 2048;
        const int m0 = (mb >> 2) * 16;
        const int nq = mb & 3;
        #pragma unroll
        for (int u = 0; u < 8; ++u) {
            int idx = t + u * 256;
            int row = idx >> 7;
            int k = (idx & 127) << 2;
            f32x4_t v = *(const f32x4_t*)&raw[(size_t)(m0 + row) * DM_ + k];
            uint2 p;
            p.x = bpack(v[1], v[0]);
            p.y = bpack(v[3], v[2]);
            *(uint2*)&S.m.Rs[row][k] = p;
        }
        __syncthreads();
        const int wave = t >> 6;
        const int lane = t & 63;
        const int lrow = lane & 15;
        const int lgrp = lane >> 4;
        const int n = nq * 64 + wave * 16 + lrow;

        f32x4_t acc = (f32x4_t){0.f, 0.f, 0.f, 0.f};
        const float* wcol = w1 + n;    // w1[k][n], stride DH_
        #pragma unroll
        for (int s = 0; s < 16; ++s) {
            bf16x8_t a = *(const bf16x8_t*)&S.m.Rs[lrow][s * 32 + lgrp * 8];
            const float* wp = wcol + (size_t)(s * 32 + lgrp * 8) * DH_;
            bf16x8_t bfr;
            #pragma unroll
            for (int j = 0; j < 8; ++j) bfr[j] = to_bf16(wp[(size_t)j * DH_]);
            acc = __builtin_amdgcn_mfma_f32_16x16x32_bf16(a, bfr, acc, 0, 0, 0);
        }
        const float b1v = b1[n];
        const float w2v = w2[n];
        float rowpart[4];
        #pragma unroll
        for (int r = 0; r < 4; ++r) {
            float h = acc[r] + b1v;
            h = h > 0.f ? h : 0.f;
            rowpart[r] = h * w2v;
        }
        #pragma unroll
        for (int r = 0; r < 4; ++r) {
            float v = rowpart[r];
            v += __shfl_xor(v, 1);
            v += __shfl_xor(v, 2);
            v += __shfl_xor(v, 4);
            v += __shfl_xor(v, 8);
            if (lrow == 0) S.m.part[wave][lgrp * 4 + r] = v;
        }
        __syncthreads();
        if (t < 16)
            fused4[nq * (B_ * L_) + m0 + t] =
                S.m.part[0][t] + S.m.part[1][t] + S.m.part[2][t] + S.m.part[3][t];
    }
}

// ---------------- flash attention: QBLK=64, 2 s-tiles per barrier ------------
// K/V arrive in the exact LDS layout (perm + row&7 swizzle baked by prep).
// fused is 4 unique-writer partials; momentum table built once in prologue.
__global__ __launch_bounds__(256) void attn_kernel(
        const float* __restrict__ Q, const bf16_t* __restrict__ Kp,
        const bf16_t* __restrict__ Vs, const float* __restrict__ fused4,
        const float* __restrict__ alpha_trend, float* __restrict__ out) {
    __shared__ __align__(16) bf16_t Ks[2][128][64];   // [buf][2 tiles][perm rows]
    __shared__ __align__(16) bf16_t Vt[2][128][64];
    __shared__ __align__(16) float moms_all[2048];

    const int bid = blockIdx.x;
    const int bh  = bid & 31;
    const int grp = bid >> 5;
    // balanced pairing: consecutive bids alternate heavy/light (sum 32 steps)
    const int qt  = (grp & 1) ? (grp >> 1) : 31 - (grp >> 1);
    const int h = bh & 15, b = bh >> 4;
    const int q0 = qt << 6;
    const int npairs = (qt + 2) >> 1;  // 128-key pair-steps
    const int tid = threadIdx.x;
    const int wave = tid >> 6, lane = tid & 63;
    const int lrow = lane & 15, lgrp = lane >> 4;

    const float c1 = 0.18033688f;      // 0.125 * log2(e)
    const float ascale2 = alpha_trend[h] * c1;
    const size_t bl = (size_t)b * L_;
    const int qw0 = q0 + wave * 16;

    const bf16_t* Kb = Kp + (size_t)bh * 131072;   // 32 tiles * 4096 el
    const bf16_t* Vb = Vs + (size_t)bh * 131072;   // 64 rows * 2048 el
    const float* f4 = fused4 + bl;     // + nq*4096 per partial

    // momentum table: built once (sums the 4 mlp partials; L3-hot)
    #pragma unroll
    for (int u = 0; u < 8; ++u) {
        int i = tid + u * 256;
        float mv = 0.f;
        if (i > 0) {
            float f0 = f4[i]     + f4[4096 + i]     + f4[8192 + i]     + f4[12288 + i];
            float fm = f4[i - 1] + f4[4096 + i - 1] + f4[8192 + i - 1] + f4[12288 + i - 1];
            mv = f0 - fm;
        }
        moms_all[i] = mv;
    }

    // Q fragments, prescaled by c1 (RNE, once)
    bf16x8_t a_lo, a_hi;
    {
        const float* qp = Q + ((bl + qw0 + lrow) * H_ + h) * E_ + lgrp * 8;
        f32x4_t v0 = *(const f32x4_t*)(qp);
        f32x4_t v1 = *(const f32x4_t*)(qp + 4);
        f32x4_t v2 = *(const f32x4_t*)(qp + 32);
        f32x4_t v3 = *(const f32x4_t*)(qp + 36);
        #pragma unroll
        for (int k = 0; k < 4; ++k) {
            a_lo[k]     = to_bf16(v0[k] * c1);
            a_lo[4 + k] = to_bf16(v1[k] * c1);
            a_hi[k]     = to_bf16(v2[k] * c1);
            a_hi[4 + k] = to_bf16(v3[k] * c1);
        }
    }
    const int qg = qw0 + lrow;
    float mq = 0.f;
    if (qg > 0) {
        float f0 = f4[qg]     + f4[4096 + qg]     + f4[8192 + qg]     + f4[12288 + qg];
        float fm = f4[qg - 1] + f4[4096 + qg - 1] + f4[8192 + qg - 1] + f4[12288 + qg - 1];
        mq = f0 - fm;
    }

    // per-lane staging sources (global layout == LDS layout, linear copy)
    const bf16_t* ksrc = Kb + wave * 512 + lane * 8;
    const bf16_t* vsrc = Vb + (size_t)(wave * 8 + (lane >> 3)) * 2048 + (lane & 7) * 8;

    f32x4_t Oacc[4];
    #pragma unroll
    for (int c = 0; c < 4; ++c) Oacc[c] = (f32x4_t){0.f, 0.f, 0.f, 0.f};
    float rowsum = 0.f;

    auto stage = [&](int p) {          // stage s-tiles 2p and 2p+1 into buf p&1
        const int nb = p & 1;
        const bf16_t* kp0 = ksrc + (size_t)p * 8192;
        gload_lds16(kp0,        &Ks[nb][wave * 8][0]);
        gload_lds16(kp0 + 2048, &Ks[nb][wave * 8 + 32][0]);
        gload_lds16(kp0 + 4096, &Ks[nb][64 + wave * 8][0]);
        gload_lds16(kp0 + 6144, &Ks[nb][64 + wave * 8 + 32][0]);
        const bf16_t* vp0 = vsrc + p * 128;
        gload_lds16(vp0,                  &Vt[nb][wave * 8][0]);
        gload_lds16(vp0 + 32 * 2048,      &Vt[nb][wave * 8 + 32][0]);
        gload_lds16(vp0 + 64,             &Vt[nb][64 + wave * 8][0]);
        gload_lds16(vp0 + 64 + 32 * 2048, &Vt[nb][64 + wave * 8 + 32][0]);
    };

    stage(0);
    for (int p = 0; p < npairs; ++p) {
        __syncthreads();               // drains buf's async loads (vmcnt 0)
        if (p + 1 < npairs) stage(p + 1);
        const int nb = p & 1;
        const int bb = lrow & 7;       // read-side swizzle (matches prep)

        #pragma unroll
        for (int sub = 0; sub < 2; ++sub) {
            const int tile = 2 * p + sub;
            const int s0 = tile << 6;
            if (s0 > qw0) continue;    // padding tile (wave-uniform skip)

            const char* ksb = (const char*)&Ks[nb][sub * 64][0];
            const char* vtb = (const char*)&Vt[nb][sub * 64][0];

            // S^T = K Q^T (swapped operands; log2 domain via Q prescale)
            f32x4_t Sacc[4];
            #pragma unroll
            for (int c = 0; c < 4; ++c) Sacc[c] = (f32x4_t){0.f, 0.f, 0.f, 0.f};
            __builtin_amdgcn_s_setprio(1);
            #pragma unroll
            for (int c = 0; c < 4; ++c) {
                const char* kr = ksb + (c * 16 + lrow) * 128;
                bf16x8_t k_lo = *(const bf16x8_t*)(kr + ((lgrp ^ bb) << 4));
                bf16x8_t k_hi = *(const bf16x8_t*)(kr + (((4 + lgrp) ^ bb) << 4));
                Sacc[c] = __builtin_amdgcn_mfma_f32_16x16x32_bf16(k_lo, a_lo, Sacc[c], 0, 0, 0);
                Sacc[c] = __builtin_amdgcn_mfma_f32_16x16x32_bf16(k_hi, a_hi, Sacc[c], 0, 0, 0);
            }
            __builtin_amdgcn_s_setprio(0);

            // P = exp2(S - ascale2*|dm|)
            float rowe[4][4];
            #pragma unroll
            for (int c = 0; c < 4; ++c) {
                const int sb = lgrp * 8 + ((c & 1) << 2) + ((c >> 1) << 5);
                f32x4_t ms4 = *(const f32x4_t*)&moms_all[s0 + sb];
                #pragma unroll
                for (int r = 0; r < 4; ++r) {
                    float arg = Sacc[c][r] - ascale2 * fabsf(mq - ms4[r]);
                    rowe[c][r] = __builtin_amdgcn_exp2f(arg);
                }
            }
            if (tile == qt) {          // causal mask on diagonal tile
                #pragma unroll
                for (int c = 0; c < 4; ++c) {
                    const int sg0 = s0 + lgrp * 8 + ((c & 1) << 2) + ((c >> 1) << 5);
                    #pragma unroll
                    for (int r = 0; r < 4; ++r)
                        if (sg0 + r > qg) rowe[c][r] = 0.f;
                }
            }
            #pragma unroll
            for (int c = 0; c < 4; ++c)
                rowsum += (rowe[c][0] + rowe[c][1]) + (rowe[c][2] + rowe[c][3]);

            // O += P V : P fragments lane-local, pack to bf16
            #pragma unroll
            for (int hh = 0; hh < 2; ++hh) {
                union { unsigned u[4]; bf16x8_t v; } pa;
                pa.u[0] = bpack(rowe[2 * hh][1],     rowe[2 * hh][0]);
                pa.u[1] = bpack(rowe[2 * hh][3],     rowe[2 * hh][2]);
                pa.u[2] = bpack(rowe[2 * hh + 1][1], rowe[2 * hh + 1][0]);
                pa.u[3] = bpack(rowe[2 * hh + 1][3], rowe[2 * hh + 1][2]);
                __builtin_amdgcn_s_setprio(1);
                #pragma unroll
                for (int c2 = 0; c2 < 4; ++c2) {
                    const int row = c2 * 16 + lrow;
                    bf16x8_t bv = *(const bf16x8_t*)(vtb + row * 128 +
                                                     (((hh * 4 + lgrp) ^ bb) << 4));
                    Oacc[c2] = __builtin_amdgcn_mfma_f32_16x16x32_bf16(pa.v, bv, Oacc[c2], 0, 0, 0);
                }
                __builtin_amdgcn_s_setprio(0);
            }
        }
    }

    // epilogue: full row sums via 2 shuffles, normalize, store
    float rs = rowsum;
    rs += __shfl_xor(rs, 16);
    rs += __shfl_xor(rs, 32);
    #pragma unroll
    for (int r = 0; r < 4; ++r) {
        float inv = 1.f / __shfl(rs, lgrp * 4 + r);
        size_t orow = ((bl + qw0 + lgrp * 4 + r) * H_ + h) * D_;
        #pragma unroll
        for (int c = 0; c < 4; ++c)
            out[orow + c * 16 + lrow] = Oacc[c][r] * inv;
    }
}

extern "C" void kernel_launch(void* const* d_in, const int* in_sizes, int n_in,
                              void* d_out, int out_size, void* d_ws, size_t ws_size,
                              hipStream_t stream) {
    const float* Q     = (const float*)d_in[0];
    const float* K     = (const float*)d_in[1];
    const float* V     = (const float*)d_in[2];
    const float* raw   = (const float*)d_in[3];
    const float* w1    = (const float*)d_in[4];
    const float* b1    = (const float*)d_in[5];
    const float* w2    = (const float*)d_in[6];
    const float* alpha = (const float*)d_in[8];
    float* out = (float*)d_out;

    float* fused4 = (float*)d_ws;                      // 4 x 4096 f32 partials
    bf16_t* Kp    = (bf16_t*)(fused4 + 4 * B_ * L_);   // 8 MB
    bf16_t* Vs    = Kp + (size_t)B_ * H_ * L_ * E_;    // 8 MB

    prep_mlp_kernel<<<3072, 256, 0, stream>>>(K, Kp, V, Vs, raw, w1, b1, w2, fused4);
    attn_kernel<<<B_ * H_ * (L_ / 64), 256, 0, stream>>>(Q, Kp, Vs, fused4, alpha, out);
}

// Round 8
// 165.899 us; speedup vs baseline: 1.0838x; 1.0064x over previous
//
#include <hip/hip_runtime.h>
#include <math.h>

#define B_ 2
#define L_ 2048
#define H_ 16
#define E_ 64
#define D_ 64
#define DM_ 512
#define DH_ 256

typedef __bf16 bf16_t;
typedef bf16_t bf16x8_t __attribute__((ext_vector_type(8)));
typedef float f32x4_t __attribute__((ext_vector_type(4)));

// pack two floats to bf16x2 (round-up-at-halfway; 2 add + 1 perm)
__device__ __forceinline__ unsigned bpack(float hi, float lo) {
    unsigned uh = __float_as_uint(hi) + 0x8000u;
    unsigned ul = __float_as_uint(lo) + 0x8000u;
    return __builtin_amdgcn_perm(uh, ul, 0x07060302u);
}

__device__ __forceinline__ bf16_t to_bf16(float f) {
    union { float f; unsigned u; } x; x.f = f;
    unsigned r = (x.u + 0x7fffu + ((x.u >> 16) & 1u)) >> 16;
    union { unsigned short s; bf16_t b; } y; y.s = (unsigned short)r;
    return y.b;
}

// async 16B global->LDS copy; HW dest = (wave-uniform base) + lane*16
__device__ __forceinline__ void gload_lds16(const bf16_t* g, bf16_t* l) {
    __builtin_amdgcn_global_load_lds(
        (const __attribute__((address_space(1))) unsigned int*)g,
        (__attribute__((address_space(3))) unsigned int*)l, 16, 0, 0);
}

// K row permutation (makes swapped-QK^T S-values land in PV A-frag layout):
// p(s) = s[1:0] | s[3]<<2 | s[4]<<3 | s[2]<<4 | s[5]<<5
__device__ __forceinline__ int permK(int sl) {
    return (sl & 3) | (((sl >> 3) & 1) << 2) | (((sl >> 4) & 1) << 3)
         | (((sl >> 2) & 1) << 4) | (((sl >> 5) & 1) << 5);
}

// ---------------- merged prep + MLP (no cross-block dependencies) ------------
// blocks [0,1024):    K [b][s][h][e] f32 -> Kp (perm + row&7 slot swizzle) bf16
// blocks [1024,2048): V -> Vs [bh][d][tile*64 + swizzled s] bf16
// blocks [2048,3072): mlp quarter: fused4[nq][m] = sum_n relu(raw@w1+b1)*w2
__global__ __launch_bounds__(256) void prep_mlp_kernel(
        const float* __restrict__ K, bf16_t* __restrict__ Kp,
        const float* __restrict__ V, bf16_t* __restrict__ Vs,
        const float* __restrict__ raw, const float* __restrict__ w1,
        const float* __restrict__ b1, const float* __restrict__ w2,
        float* __restrict__ fused4) {
    __shared__ union {
        bf16_t T[64][88];              // V transpose tile
        struct { bf16_t Rs[16][520]; float part[4][16]; } m;
    } S;
    const int bidx = blockIdx.x;
    const int t = threadIdx.x;

    if (bidx < 1024) {                 // ---- K convert ----
        const int bh = bidx >> 5, tile = bidx & 31;
        const int b = bh >> 4, h = bh & 15;
        const int sl = t >> 2, e0 = (t & 3) << 4;
        const float* src = K + (((size_t)b * L_ + tile * 64 + sl) * H_ + h) * E_ + e0;
        f32x4_t v0 = *(const f32x4_t*)(src);
        f32x4_t v1 = *(const f32x4_t*)(src + 4);
        f32x4_t v2 = *(const f32x4_t*)(src + 8);
        f32x4_t v3 = *(const f32x4_t*)(src + 12);
        uint4 lo, hi;
        lo.x = bpack(v0[1], v0[0]); lo.y = bpack(v0[3], v0[2]);
        lo.z = bpack(v1[1], v1[0]); lo.w = bpack(v1[3], v1[2]);
        hi.x = bpack(v2[1], v2[0]); hi.y = bpack(v2[3], v2[2]);
        hi.z = bpack(v3[1], v3[0]); hi.w = bpack(v3[3], v3[2]);
        const int r = permK(sl);
        const int bb = r & 7;          // low row bits -> bank spread
        bf16_t* drow = Kp + ((size_t)(bh * 32 + tile) * 64 + r) * 64;
        *(uint4*)(drow + ((((e0 >> 3)    ) ^ bb) << 3)) = lo;
        *(uint4*)(drow + ((((e0 >> 3) + 1) ^ bb) << 3)) = hi;
        return;
    }

    if (bidx < 2048) {                 // ---- V convert/transpose ----
        const int idx = bidx - 1024;
        const int bh = idx >> 5, tile = idx & 31;
        const int b = bh >> 4, h = bh & 15;
        const int sl = t >> 2, d0 = (t & 3) << 4;
        const float* src = V + (((size_t)b * L_ + tile * 64 + sl) * H_ + h) * D_ + d0;
        f32x4_t v0 = *(const f32x4_t*)(src);
        f32x4_t v1 = *(const f32x4_t*)(src + 4);
        f32x4_t v2 = *(const f32x4_t*)(src + 8);
        f32x4_t v3 = *(const f32x4_t*)(src + 12);
        uint4 lo, hi;
        lo.x = bpack(v0[1], v0[0]); lo.y = bpack(v0[3], v0[2]);
        lo.z = bpack(v1[1], v1[0]); lo.w = bpack(v1[3], v1[2]);
        hi.x = bpack(v2[1], v2[0]); hi.y = bpack(v2[3], v2[2]);
        hi.z = bpack(v3[1], v3[0]); hi.w = bpack(v3[3], v3[2]);
        *(uint4*)&S.T[sl][d0]     = lo;
        *(uint4*)&S.T[sl][d0 + 8] = hi;
        __syncthreads();
        const int d = t & 63, bd = d & 7;  // low row bits -> bank spread
        bf16_t* drow = Vs + ((size_t)bh * 64 + d) * 2048 + tile * 64;
        #pragma unroll
        for (int gg = 0; gg < 2; ++gg) {
            int qb = (t >> 6) + gg * 4;
            int slb = (qb ^ bd) << 3;        // content(slot q) = V[(q^bd)*8+j][d]
            union { unsigned short u[8]; uint4 q; } acc;
            #pragma unroll
            for (int j = 0; j < 8; ++j) {
                union { bf16_t b; unsigned short s; } x; x.b = S.T[slb + j][d];
                acc.u[j] = x.s;
            }
            *(uint4*)(drow + qb * 8) = acc.q;
        }
        return;
    }

    {                                  // ---- mlp quarter (direct w1 reads) ----
        const int mb = bidx - 2048;
        const int m0 = (mb >> 2) * 16;
        const int nq = mb & 3;
        #pragma unroll
        for (int u = 0; u < 8; ++u) {
            int idx = t + u * 256;
            int row = idx >> 7;
            int k = (idx & 127) << 2;
            f32x4_t v = *(const f32x4_t*)&raw[(size_t)(m0 + row) * DM_ + k];
            uint2 p;
            p.x = bpack(v[1], v[0]);
            p.y = bpack(v[3], v[2]);
            *(uint2*)&S.m.Rs[row][k] = p;
        }
        __syncthreads();
        const int wave = t >> 6;
        const int lane = t & 63;
        const int lrow = lane & 15;
        const int lgrp = lane >> 4;
        const int n = nq * 64 + wave * 16 + lrow;

        f32x4_t acc = (f32x4_t){0.f, 0.f, 0.f, 0.f};
        const float* wcol = w1 + n;    // w1[k][n], stride DH_
        #pragma unroll
        for (int s = 0; s < 16; ++s) {
            bf16x8_t a = *(const bf16x8_t*)&S.m.Rs[lrow][s * 32 + lgrp * 8];
            const float* wp = wcol + (size_t)(s * 32 + lgrp * 8) * DH_;
            bf16x8_t bfr;
            #pragma unroll
            for (int j = 0; j < 8; ++j) bfr[j] = to_bf16(wp[(size_t)j * DH_]);
            acc = __builtin_amdgcn_mfma_f32_16x16x32_bf16(a, bfr, acc, 0, 0, 0);
        }
        const float b1v = b1[n];
        const float w2v = w2[n];
        float rowpart[4];
        #pragma unroll
        for (int r = 0; r < 4; ++r) {
            float h = acc[r] + b1v;
            h = h > 0.f ? h : 0.f;
            rowpart[r] = h * w2v;
        }
        #pragma unroll
        for (int r = 0; r < 4; ++r) {
            float v = rowpart[r];
            v += __shfl_xor(v, 1);
            v += __shfl_xor(v, 2);
            v += __shfl_xor(v, 4);
            v += __shfl_xor(v, 8);
            if (lrow == 0) S.m.part[wave][lgrp * 4 + r] = v;
        }
        __syncthreads();
        if (t < 16)
            fused4[nq * (B_ * L_) + m0 + t] =
                S.m.part[0][t] + S.m.part[1][t] + S.m.part[2][t] + S.m.part[3][t];
    }
}

// ---------------- flash attention: 2 s-tiles per barrier, INTERLEAVED --------
// The two 64-key sub-tiles of each pair-step are fully independent; computing
// them interleaved (dual Sacc/rowe, back-to-back MFMAs) overlaps their
// ds_read->MFMA->exp->pack->PV dependency chains instead of serializing them.
__global__ __launch_bounds__(256) void attn_kernel(
        const float* __restrict__ Q, const bf16_t* __restrict__ Kp,
        const bf16_t* __restrict__ Vs, const float* __restrict__ fused4,
        const float* __restrict__ alpha_trend, float* __restrict__ out) {
    __shared__ __align__(16) bf16_t Ks[2][128][64];   // [buf][2 tiles][perm rows]
    __shared__ __align__(16) bf16_t Vt[2][128][64];
    __shared__ __align__(16) float moms_all[2048];

    const int bid = blockIdx.x;
    const int bh  = bid & 31;
    const int grp = bid >> 5;
    // balanced pairing: consecutive bids alternate heavy/light (sum 32 steps)
    const int qt  = (grp & 1) ? (grp >> 1) : 31 - (grp >> 1);
    const int h = bh & 15, b = bh >> 4;
    const int npairs = (qt + 2) >> 1;  // 128-key pair-steps
    const int tid = threadIdx.x;
    const int wave = tid >> 6, lane = tid & 63;
    const int lrow = lane & 15, lgrp = lane >> 4;

    const float c1 = 0.18033688f;      // 0.125 * log2(e)
    const float ascale2 = alpha_trend[h] * c1;
    const size_t bl = (size_t)b * L_;
    const int qw0 = (qt << 6) + wave * 16;

    const bf16_t* Kb = Kp + (size_t)bh * 131072;   // 32 tiles * 4096 el
    const bf16_t* Vb = Vs + (size_t)bh * 131072;   // 64 rows * 2048 el
    const float* f4 = fused4 + bl;     // + nq*4096 per partial

    // momentum table: built once (sums the 4 mlp partials; L3-hot)
    #pragma unroll
    for (int u = 0; u < 8; ++u) {
        int i = tid + u * 256;
        float mv = 0.f;
        if (i > 0) {
            float f0 = f4[i]     + f4[4096 + i]     + f4[8192 + i]     + f4[12288 + i];
            float fm = f4[i - 1] + f4[4096 + i - 1] + f4[8192 + i - 1] + f4[12288 + i - 1];
            mv = f0 - fm;
        }
        moms_all[i] = mv;
    }

    // Q fragments, prescaled by c1 (RNE, once)
    bf16x8_t a_lo, a_hi;
    {
        const float* qp = Q + ((bl + qw0 + lrow) * H_ + h) * E_ + lgrp * 8;
        f32x4_t v0 = *(const f32x4_t*)(qp);
        f32x4_t v1 = *(const f32x4_t*)(qp + 4);
        f32x4_t v2 = *(const f32x4_t*)(qp + 32);
        f32x4_t v3 = *(const f32x4_t*)(qp + 36);
        #pragma unroll
        for (int k = 0; k < 4; ++k) {
            a_lo[k]     = to_bf16(v0[k] * c1);
            a_lo[4 + k] = to_bf16(v1[k] * c1);
            a_hi[k]     = to_bf16(v2[k] * c1);
            a_hi[4 + k] = to_bf16(v3[k] * c1);
        }
    }
    const int qg = qw0 + lrow;
    float mq = 0.f;
    if (qg > 0) {
        float f0 = f4[qg]     + f4[4096 + qg]     + f4[8192 + qg]     + f4[12288 + qg];
        float fm = f4[qg - 1] + f4[4096 + qg - 1] + f4[8192 + qg - 1] + f4[12288 + qg - 1];
        mq = f0 - fm;
    }

    // per-lane staging sources (global layout == LDS layout, linear copy)
    const bf16_t* ksrc = Kb + wave * 512 + lane * 8;
    const bf16_t* vsrc = Vb + (size_t)(wave * 8 + (lane >> 3)) * 2048 + (lane & 7) * 8;

    f32x4_t Oacc[4];
    #pragma unroll
    for (int c = 0; c < 4; ++c) Oacc[c] = (f32x4_t){0.f, 0.f, 0.f, 0.f};
    float rowsum = 0.f;

    auto stage = [&](int p) {          // stage s-tiles 2p and 2p+1 into buf p&1
        const int nb = p & 1;
        const bf16_t* kp0 = ksrc + (size_t)p * 8192;
        gload_lds16(kp0,        &Ks[nb][wave * 8][0]);
        gload_lds16(kp0 + 2048, &Ks[nb][wave * 8 + 32][0]);
        gload_lds16(kp0 + 4096, &Ks[nb][64 + wave * 8][0]);
        gload_lds16(kp0 + 6144, &Ks[nb][64 + wave * 8 + 32][0]);
        const bf16_t* vp0 = vsrc + p * 128;
        gload_lds16(vp0,                  &Vt[nb][wave * 8][0]);
        gload_lds16(vp0 + 32 * 2048,      &Vt[nb][wave * 8 + 32][0]);
        gload_lds16(vp0 + 64,             &Vt[nb][64 + wave * 8][0]);
        gload_lds16(vp0 + 64 + 32 * 2048, &Vt[nb][64 + wave * 8 + 32][0]);
    };

    const int bb = lrow & 7;           // read-side swizzle (matches prep)

    stage(0);
    for (int p = 0; p < npairs; ++p) {
        __syncthreads();               // drains buf's async loads (vmcnt 0)
        if (p + 1 < npairs) stage(p + 1);
        const int nb = p & 1;
        const char* ksb0 = (const char*)&Ks[nb][0][0];
        const char* vtb0 = (const char*)&Vt[nb][0][0];
        const char* ksb1 = ksb0 + 64 * 128;
        const char* vtb1 = vtb0 + 64 * 128;
        const int tile0 = 2 * p;
        const int s00 = tile0 << 6;

        if ((qt & 1) || (p + 1 < npairs)) {
            // ---- interleaved: both sub-tiles valid (tile1 <= qt) ----
            const int tile1 = tile0 + 1;
            const int s01 = s00 + 64;

            f32x4_t Sacc0[4], Sacc1[4];
            #pragma unroll
            for (int c = 0; c < 4; ++c) {
                Sacc0[c] = (f32x4_t){0.f, 0.f, 0.f, 0.f};
                Sacc1[c] = (f32x4_t){0.f, 0.f, 0.f, 0.f};
            }
            __builtin_amdgcn_s_setprio(1);
            #pragma unroll
            for (int c = 0; c < 4; ++c) {
                const int ro = (c * 16 + lrow) * 128;
                const int olo = (lgrp ^ bb) << 4;
                const int ohi = ((4 + lgrp) ^ bb) << 4;
                bf16x8_t k_lo0 = *(const bf16x8_t*)(ksb0 + ro + olo);
                bf16x8_t k_hi0 = *(const bf16x8_t*)(ksb0 + ro + ohi);
                bf16x8_t k_lo1 = *(const bf16x8_t*)(ksb1 + ro + olo);
                bf16x8_t k_hi1 = *(const bf16x8_t*)(ksb1 + ro + ohi);
                Sacc0[c] = __builtin_amdgcn_mfma_f32_16x16x32_bf16(k_lo0, a_lo, Sacc0[c], 0, 0, 0);
                Sacc1[c] = __builtin_amdgcn_mfma_f32_16x16x32_bf16(k_lo1, a_lo, Sacc1[c], 0, 0, 0);
                Sacc0[c] = __builtin_amdgcn_mfma_f32_16x16x32_bf16(k_hi0, a_hi, Sacc0[c], 0, 0, 0);
                Sacc1[c] = __builtin_amdgcn_mfma_f32_16x16x32_bf16(k_hi1, a_hi, Sacc1[c], 0, 0, 0);
            }
            __builtin_amdgcn_s_setprio(0);

            float rowe0[4][4], rowe1[4][4];
            #pragma unroll
            for (int c = 0; c < 4; ++c) {
                const int sb = lgrp * 8 + ((c & 1) << 2) + ((c >> 1) << 5);
                f32x4_t ms0 = *(const f32x4_t*)&moms_all[s00 + sb];
                f32x4_t ms1 = *(const f32x4_t*)&moms_all[s01 + sb];
                #pragma unroll
                for (int r = 0; r < 4; ++r) {
                    rowe0[c][r] = __builtin_amdgcn_exp2f(
                        Sacc0[c][r] - ascale2 * fabsf(mq - ms0[r]));
                    rowe1[c][r] = __builtin_amdgcn_exp2f(
                        Sacc1[c][r] - ascale2 * fabsf(mq - ms1[r]));
                }
            }
            if (tile1 == qt) {         // only tile1 can be diagonal here
                #pragma unroll
                for (int c = 0; c < 4; ++c) {
                    const int sg0 = s01 + lgrp * 8 + ((c & 1) << 2) + ((c >> 1) << 5);
                    #pragma unroll
                    for (int r = 0; r < 4; ++r)
                        if (sg0 + r > qg) rowe1[c][r] = 0.f;
                }
            }
            #pragma unroll
            for (int c = 0; c < 4; ++c)
                rowsum += ((rowe0[c][0] + rowe0[c][1]) + (rowe0[c][2] + rowe0[c][3]))
                        + ((rowe1[c][0] + rowe1[c][1]) + (rowe1[c][2] + rowe1[c][3]));

            #pragma unroll
            for (int hh = 0; hh < 2; ++hh) {
                union { unsigned u[4]; bf16x8_t v; } pa0, pa1;
                pa0.u[0] = bpack(rowe0[2 * hh][1],     rowe0[2 * hh][0]);
                pa0.u[1] = bpack(rowe0[2 * hh][3],     rowe0[2 * hh][2]);
                pa0.u[2] = bpack(rowe0[2 * hh + 1][1], rowe0[2 * hh + 1][0]);
                pa0.u[3] = bpack(rowe0[2 * hh + 1][3], rowe0[2 * hh + 1][2]);
                pa1.u[0] = bpack(rowe1[2 * hh][1],     rowe1[2 * hh][0]);
                pa1.u[1] = bpack(rowe1[2 * hh][3],     rowe1[2 * hh][2]);
                pa1.u[2] = bpack(rowe1[2 * hh + 1][1], rowe1[2 * hh + 1][0]);
                pa1.u[3] = bpack(rowe1[2 * hh + 1][3], rowe1[2 * hh + 1][2]);
                __builtin_amdgcn_s_setprio(1);
                #pragma unroll
                for (int c2 = 0; c2 < 4; ++c2) {
                    const int ro = (c2 * 16 + lrow) * 128;
                    const int ov = ((hh * 4 + lgrp) ^ bb) << 4;
                    bf16x8_t bv0 = *(const bf16x8_t*)(vtb0 + ro + ov);
                    bf16x8_t bv1 = *(const bf16x8_t*)(vtb1 + ro + ov);
                    Oacc[c2] = __builtin_amdgcn_mfma_f32_16x16x32_bf16(pa0.v, bv0, Oacc[c2], 0, 0, 0);
                    Oacc[c2] = __builtin_amdgcn_mfma_f32_16x16x32_bf16(pa1.v, bv1, Oacc[c2], 0, 0, 0);
                }
                __builtin_amdgcn_s_setprio(0);
            }
        } else {
            // ---- single: last pair of even qt; tile0 == qt (diagonal) ----
            f32x4_t Sacc[4];
            #pragma unroll
            for (int c = 0; c < 4; ++c) Sacc[c] = (f32x4_t){0.f, 0.f, 0.f, 0.f};
            __builtin_amdgcn_s_setprio(1);
            #pragma unroll
            for (int c = 0; c < 4; ++c) {
                const int ro = (c * 16 + lrow) * 128;
                bf16x8_t k_lo = *(const bf16x8_t*)(ksb0 + ro + ((lgrp ^ bb) << 4));
                bf16x8_t k_hi = *(const bf16x8_t*)(ksb0 + ro + (((4 + lgrp) ^ bb) << 4));
                Sacc[c] = __builtin_amdgcn_mfma_f32_16x16x32_bf16(k_lo, a_lo, Sacc[c], 0, 0, 0);
                Sacc[c] = __builtin_amdgcn_mfma_f32_16x16x32_bf16(k_hi, a_hi, Sacc[c], 0, 0, 0);
            }
            __builtin_amdgcn_s_setprio(0);

            float rowe[4][4];
            #pragma unroll
            for (int c = 0; c < 4; ++c) {
                const int sb = lgrp * 8 + ((c & 1) << 2) + ((c >> 1) << 5);
                f32x4_t ms4 = *(const f32x4_t*)&moms_all[s00 + sb];
                #pragma unroll
                for (int r = 0; r < 4; ++r)
                    rowe[c][r] = __builtin_amdgcn_exp2f(
                        Sacc[c][r] - ascale2 * fabsf(mq - ms4[r]));
            }
            #pragma unroll
            for (int c = 0; c < 4; ++c) {     // tile0 == qt: causal mask
                const int sg0 = s00 + lgrp * 8 + ((c & 1) << 2) + ((c >> 1) << 5);
                #pragma unroll
                for (int r = 0; r < 4; ++r)
                    if (sg0 + r > qg) rowe[c][r] = 0.f;
            }
            #pragma unroll
            for (int c = 0; c < 4; ++c)
                rowsum += (rowe[c][0] + rowe[c][1]) + (rowe[c][2] + rowe[c][3]);

            #pragma unroll
            for (int hh = 0; hh < 2; ++hh) {
                union { unsigned u[4]; bf16x8_t v; } pa;
                pa.u[0] = bpack(rowe[2 * hh][1],     rowe[2 * hh][0]);
                pa.u[1] = bpack(rowe[2 * hh][3],     rowe[2 * hh][2]);
                pa.u[2] = bpack(rowe[2 * hh + 1][1], rowe[2 * hh + 1][0]);
                pa.u[3] = bpack(rowe[2 * hh + 1][3], rowe[2 * hh + 1][2]);
                __builtin_amdgcn_s_setprio(1);
                #pragma unroll
                for (int c2 = 0; c2 < 4; ++c2) {
                    const int ro = (c2 * 16 + lrow) * 128;
                    bf16x8_t bv = *(const bf16x8_t*)(vtb0 + ro +
                                                     (((hh * 4 + lgrp) ^ bb) << 4));
                    Oacc[c2] = __builtin_amdgcn_mfma_f32_16x16x32_bf16(pa.v, bv, Oacc[c2], 0, 0, 0);
                }
                __builtin_amdgcn_s_setprio(0);
            }
        }
    }

    // epilogue: full row sums via 2 shuffles, normalize, store
    float rs = rowsum;
    rs += __shfl_xor(rs, 16);
    rs += __shfl_xor(rs, 32);
    #pragma unroll
    for (int r = 0; r < 4; ++r) {
        float inv = 1.f / __shfl(rs, lgrp * 4 + r);
        size_t orow = ((bl + qw0 + lgrp * 4 + r) * H_ + h) * D_;
        #pragma unroll
        for (int c = 0; c < 4; ++c)
            out[orow + c * 16 + lrow] = Oacc[c][r] * inv;
    }
}

extern "C" void kernel_launch(void* const* d_in, const int* in_sizes, int n_in,
                              void* d_out, int out_size, void* d_ws, size_t ws_size,
                              hipStream_t stream) {
    const float* Q     = (const float*)d_in[0];
    const float* K     = (const float*)d_in[1];
    const float* V     = (const float*)d_in[2];
    const float* raw   = (const float*)d_in[3];
    const float* w1    = (const float*)d_in[4];
    const float* b1    = (const float*)d_in[5];
    const float* w2    = (const float*)d_in[6];
    const float* alpha = (const float*)d_in[8];
    float* out = (float*)d_out;

    float* fused4 = (float*)d_ws;                      // 4 x 4096 f32 partials
    bf16_t* Kp    = (bf16_t*)(fused4 + 4 * B_ * L_);   // 8 MB
    bf16_t* Vs    = Kp + (size_t)B_ * H_ * L_ * E_;    // 8 MB

    prep_mlp_kernel<<<3072, 256, 0, stream>>>(K, Kp, V, Vs, raw, w1, b1, w2, fused4);
    attn_kernel<<<B_ * H_ * (L_ / 64), 256, 0, stream>>>(Q, Kp, Vs, fused4, alpha, out);
}